// Round 1
// baseline (2775.101 us; speedup 1.0000x reference)
//
#include <hip/hip_runtime.h>
#include <hip/hip_bf16.h>

#define B_ 2
#define T_ 128
#define U_ 64
#define H_ 1024
#define NO_ 5001

typedef __attribute__((ext_vector_type(8))) short bf16x8;
typedef __attribute__((ext_vector_type(4))) float f32x4;
typedef __attribute__((ext_vector_type(4))) unsigned int uint4v;

__device__ __forceinline__ float bf2f(unsigned short s) {
  unsigned int u = ((unsigned int)s) << 16;
  float f; __builtin_memcpy(&f, &u, 4); return f;
}
__device__ __forceinline__ unsigned short f2bf(float f) {
  unsigned int u; __builtin_memcpy(&u, &f, 4);
  u = u + 0x7FFFu + ((u >> 16) & 1u);   // round-to-nearest-even
  return (unsigned short)(u >> 16);
}

// ---------------- f32 -> bf16 convert (vectorized) ----------------
__global__ void k_cvt(const float* __restrict__ src, unsigned short* __restrict__ dst, int n4) {
  int i = blockIdx.x * 256 + threadIdx.x;
  if (i >= n4) return;
  const float4 v = ((const float4*)src)[i];
  ushort4 o;
  o.x = f2bf(v.x); o.y = f2bf(v.y); o.z = f2bf(v.z); o.w = f2bf(v.w);
  ((ushort4*)dst)[i] = o;
}

// ---------------- embedding gather -> bf16 ----------------
__global__ void k_embed(const int* __restrict__ tg, const float* __restrict__ em,
                        unsigned short* __restrict__ x0) {
  int idx = blockIdx.x * 256 + threadIdx.x;   // [0, B*U*H/4)
  int bu = idx >> 8;                          // H/4 = 256 chunks per row
  int kc = (idx & 255) << 2;
  int t = tg[bu];
  const float4 v = *(const float4*)&em[(long)t * H_ + kc];
  ushort4 o; o.x = f2bf(v.x); o.y = f2bf(v.y); o.z = f2bf(v.z); o.w = f2bf(v.w);
  *(ushort4*)&x0[bu * H_ + kc] = o;
}

// ---------------- generic bf16 MFMA GEMM:  C[M,N] = A[M,K] * W[N,K]^T + b1 + b2 ----------------
// M % 128 == 0, K % 32 == 0; N may have a tail (masked).
#define LST 40   // LDS row stride in bf16 elems (32 + 8 pad -> even bank spread)

__global__ __launch_bounds__(256) void gemm_bt(
    const unsigned short* __restrict__ A, const unsigned short* __restrict__ W,
    const float* __restrict__ b1, const float* __restrict__ b2,
    float* __restrict__ C, int M, int N, int K)
{
  __shared__ unsigned short As[128 * LST];
  __shared__ unsigned short Bs[128 * LST];
  const int tid = threadIdx.x;
  const int n0 = blockIdx.x * 128, m0 = blockIdx.y * 128;
  const int lane = tid & 63, w = tid >> 6;
  const int wr = (w >> 1) * 64, wc = (w & 1) * 64;   // wave's 64x64 sub-tile
  const int lr = lane & 15, lk = (lane >> 4) * 8;
  f32x4 acc[4][4] = {};

  for (int k0 = 0; k0 < K; k0 += 32) {
    // stage A and W tiles (128 rows x 32 bf16), reg-staged so LDS rows can be padded
#pragma unroll
    for (int s = 0; s < 2; ++s) {
      int idx = s * 256 + tid;          // 512 chunks of 16B
      int row = idx >> 2, c8 = (idx & 3) * 8;
      uint4v va = *(const uint4v*)&A[(m0 + row) * K + k0 + c8];
      *(uint4v*)&As[row * LST + c8] = va;
      uint4v vb = {0u, 0u, 0u, 0u};
      int nrow = n0 + row;
      if (nrow < N) vb = *(const uint4v*)&W[nrow * K + k0 + c8];
      *(uint4v*)&Bs[row * LST + c8] = vb;
    }
    __syncthreads();
    bf16x8 aF[4], bF[4];
#pragma unroll
    for (int i = 0; i < 4; ++i) {
      aF[i] = *(const bf16x8*)&As[(wr + i * 16 + lr) * LST + lk];
      bF[i] = *(const bf16x8*)&Bs[(wc + i * 16 + lr) * LST + lk];
    }
#pragma unroll
    for (int i = 0; i < 4; ++i)
#pragma unroll
      for (int j = 0; j < 4; ++j)
        acc[i][j] = __builtin_amdgcn_mfma_f32_16x16x32_bf16(aF[i], bF[j], acc[i][j], 0, 0, 0);
    __syncthreads();
  }

  // epilogue: C/D layout col=lane&15, row=(lane>>4)*4+r
  const int lq = (lane >> 4) * 4;
#pragma unroll
  for (int j = 0; j < 4; ++j) {
    int col = n0 + wc + j * 16 + lr;
    if (col >= N) continue;
    float bb = 0.f;
    if (b1) bb += b1[col];
    if (b2) bb += b2[col];
#pragma unroll
    for (int i = 0; i < 4; ++i) {
      int rowg = m0 + wr + i * 16 + lq;
#pragma unroll
      for (int r = 0; r < 4; ++r)
        C[(long)(rowg + r) * N + col] = acc[i][j][r] + bb;
    }
  }
}

// ---------------- one LSTM time step (f32 math, bf16 weights) ----------------
// grid 32 blocks x 256 thr; block handles j in [bid*32, bid*32+32) for all 4 gates, both batches.
__global__ __launch_bounds__(256) void lstm_step(
    const float* __restrict__ xg,        // [B*U][4096] input projections (+bias)
    const unsigned short* __restrict__ Whh,  // [4096][1024] bf16
    const float* __restrict__ hin,       // [B][1024] (valid for u>0)
    float* __restrict__ hout,            // [B][1024]
    float* __restrict__ cst,             // [B][1024]
    unsigned short* __restrict__ xout,   // [B*U][1024] bf16 layer output
    int u)
{
  __shared__ float hs[2 * H_];
  __shared__ float gb[256];
  const int tid = threadIdx.x;
  const int b = tid >> 7, gate = (tid >> 5) & 3, jo = tid & 31;
  const int j = blockIdx.x * 32 + jo;
  float acc = 0.f;
  if (u > 0) {
    ((float4*)hs)[tid]       = ((const float4*)hin)[tid];
    ((float4*)hs)[tid + 256] = ((const float4*)hin)[tid + 256];
    __syncthreads();
    const unsigned short* wrow = Whh + (gate * H_ + j) * H_;
    const float* hb = hs + b * H_;
    float a0 = 0.f, a1 = 0.f;
#pragma unroll 4
    for (int kk = 0; kk < H_; kk += 8) {
      ushort4 w0 = *(const ushort4*)(wrow + kk);
      ushort4 w1 = *(const ushort4*)(wrow + kk + 4);
      a0 += bf2f(w0.x) * hb[kk + 0] + bf2f(w0.y) * hb[kk + 1]
          + bf2f(w0.z) * hb[kk + 2] + bf2f(w0.w) * hb[kk + 3];
      a1 += bf2f(w1.x) * hb[kk + 4] + bf2f(w1.y) * hb[kk + 5]
          + bf2f(w1.z) * hb[kk + 6] + bf2f(w1.w) * hb[kk + 7];
    }
    acc = a0 + a1;
  }
  gb[tid] = xg[(b * U_ + u) * 4096 + gate * H_ + j] + acc;   // tid == b*128+gate*32+jo
  __syncthreads();
  if (tid < 64) {
    const int b2 = tid >> 5, jo2 = tid & 31;
    const int j2 = blockIdx.x * 32 + jo2;
    const int base = b2 * 128;
    float gi = gb[base + jo2];
    float gf = gb[base + 32 + jo2];
    float gg = gb[base + 64 + jo2];
    float go = gb[base + 96 + jo2];
    float i_ = 1.f / (1.f + expf(-gi));
    float f_ = 1.f / (1.f + expf(-gf));
    float g_ = tanhf(gg);
    float o_ = 1.f / (1.f + expf(-go));
    float cp = (u > 0) ? cst[b2 * H_ + j2] : 0.f;
    float c = f_ * cp + i_ * g_;
    float h = o_ * tanhf(c);
    cst[b2 * H_ + j2] = c;
    hout[b2 * H_ + j2] = h;
    xout[(b2 * U_ + u) * H_ + j2] = f2bf(h);
  }
}

// ---------------- joint = bf16(relu(enc_p[b,t,:] + prd_p[b,u,:])) ----------------
__global__ void k_joint(const float* __restrict__ ep, const float* __restrict__ pp,
                        unsigned short* __restrict__ jt)
{
  int idx = blockIdx.x * 256 + threadIdx.x;  // per float4; total 16384*256
  int m = idx >> 8;
  int kc = (idx & 255) << 2;
  int erow = m >> 6;                          // b*T + t
  int prow = (m >> 13) * U_ + (m & 63);       // b*U + u
  const float4 e = *(const float4*)&ep[erow * H_ + kc];
  const float4 p = *(const float4*)&pp[prow * H_ + kc];
  float4 s;
  s.x = fmaxf(e.x + p.x, 0.f); s.y = fmaxf(e.y + p.y, 0.f);
  s.z = fmaxf(e.z + p.z, 0.f); s.w = fmaxf(e.w + p.w, 0.f);
  ushort4 o; o.x = f2bf(s.x); o.y = f2bf(s.y); o.z = f2bf(s.z); o.w = f2bf(s.w);
  *(ushort4*)&jt[m * H_ + kc] = o;
}

extern "C" void kernel_launch(void* const* d_in, const int* in_sizes, int n_in,
                              void* d_out, int out_size, void* d_ws, size_t ws_size,
                              hipStream_t stream)
{
  const float* enc   = (const float*)d_in[0];
  const int*   tg    = (const int*)d_in[1];
  const float* em    = (const float*)d_in[2];
  const float* Wih   = (const float*)d_in[3];
  const float* Whh   = (const float*)d_in[4];
  const float* bih   = (const float*)d_in[5];
  const float* bhh   = (const float*)d_in[6];
  const float* encW  = (const float*)d_in[7];
  const float* encB  = (const float*)d_in[8];
  const float* prdW  = (const float*)d_in[9];
  const float* prdB  = (const float*)d_in[10];
  const float* outW  = (const float*)d_in[11];
  const float* outB  = (const float*)d_in[12];
  float* out = (float*)d_out;
  char* ws = (char*)d_ws;

  // workspace layout (bytes)
  unsigned short* outW_bf = (unsigned short*)(ws + 0);         // 5001*1024*2
  unsigned short* Wih_bf  = (unsigned short*)(ws + 10242048);  // 2*4096*1024*2
  unsigned short* Whh_bf  = (unsigned short*)(ws + 27019264);  // 2*4096*1024*2
  unsigned short* encW_bf = (unsigned short*)(ws + 43796480);  // 1024*1024*2
  unsigned short* prdW_bf = (unsigned short*)(ws + 45893632);  // 1024*1024*2
  unsigned short* enc_bf  = (unsigned short*)(ws + 47990784);  // 256*1024*2
  unsigned short* x0_bf   = (unsigned short*)(ws + 48515072);  // 128*1024*2
  unsigned short* x1_bf   = (unsigned short*)(ws + 48777216);  // 128*1024*2
  unsigned short* x2_bf   = (unsigned short*)(ws + 49039360);  // 128*1024*2
  float* xg  = (float*)(ws + 49301504);                        // 128*4096*4
  float* h0  = (float*)(ws + 51398656);                        // 2048*4
  float* h1  = (float*)(ws + 51406848);                        // 2048*4
  float* cst = (float*)(ws + 51415040);                        // 2048*4
  float* ep  = (float*)(ws + 51423232);                        // 256*1024*4
  float* pp  = (float*)(ws + 52471808);                        // 128*1024*4
  unsigned short* jt = (unsigned short*)(ws + 52996096);       // 16384*1024*2

  // weight / activation conversions to bf16
  {
    int n4;
    n4 = (NO_ * H_) >> 2;        k_cvt<<<(n4 + 255) / 256, 256, 0, stream>>>(outW, outW_bf, n4);
    n4 = (2 * 4096 * H_) >> 2;   k_cvt<<<(n4 + 255) / 256, 256, 0, stream>>>(Wih, Wih_bf, n4);
    n4 = (2 * 4096 * H_) >> 2;   k_cvt<<<(n4 + 255) / 256, 256, 0, stream>>>(Whh, Whh_bf, n4);
    n4 = (H_ * H_) >> 2;         k_cvt<<<(n4 + 255) / 256, 256, 0, stream>>>(encW, encW_bf, n4);
    n4 = (H_ * H_) >> 2;         k_cvt<<<(n4 + 255) / 256, 256, 0, stream>>>(prdW, prdW_bf, n4);
    n4 = (B_ * T_ * H_) >> 2;    k_cvt<<<(n4 + 255) / 256, 256, 0, stream>>>(enc, enc_bf, n4);
  }
  k_embed<<<(B_ * U_ * H_ / 4) / 256, 256, 0, stream>>>(tg, em, x0_bf);

  // ---- LSTM layer 0 ----
  gemm_bt<<<dim3(32, 1), 256, 0, stream>>>(x0_bf, Wih_bf, bih, bhh, xg, B_ * U_, 4096, H_);
  for (int u = 0; u < U_; ++u) {
    const float* hin = (u & 1) ? h1 : h0;
    float* houtp     = (u & 1) ? h0 : h1;
    lstm_step<<<32, 256, 0, stream>>>(xg, Whh_bf, hin, houtp, cst, x1_bf, u);
  }
  // ---- LSTM layer 1 ----
  gemm_bt<<<dim3(32, 1), 256, 0, stream>>>(x1_bf, Wih_bf + 4096 * H_, bih + 4096, bhh + 4096,
                                           xg, B_ * U_, 4096, H_);
  for (int u = 0; u < U_; ++u) {
    const float* hin = (u & 1) ? h1 : h0;
    float* houtp     = (u & 1) ? h0 : h1;
    lstm_step<<<32, 256, 0, stream>>>(xg, Whh_bf + 4096 * H_, hin, houtp, cst, x2_bf, u);
  }

  // ---- projections ----
  gemm_bt<<<dim3(8, 2), 256, 0, stream>>>(enc_bf, encW_bf, encB, nullptr, ep, B_ * T_, H_, H_);
  gemm_bt<<<dim3(8, 1), 256, 0, stream>>>(x2_bf, prdW_bf, prdB, nullptr, pp, B_ * U_, H_, H_);

  // ---- joint + logits ----
  k_joint<<<16384, 256, 0, stream>>>(ep, pp, jt);
  gemm_bt<<<dim3((NO_ + 127) / 128, B_ * T_ * U_ / 128), 256, 0, stream>>>(
      jt, outW_bf, outB, nullptr, out, B_ * T_ * U_, NO_, H_);
}

// Round 3
// 2760.101 us; speedup vs baseline: 1.0054x; 1.0054x over previous
//
#include <hip/hip_runtime.h>
#include <hip/hip_bf16.h>

#define B_ 2
#define T_ 128
#define U_ 64
#define H_ 1024
#define NO_ 5001

typedef __attribute__((ext_vector_type(8))) short bf16x8;
typedef __attribute__((ext_vector_type(4))) float f32x4;
typedef __attribute__((ext_vector_type(4))) unsigned int uint4v;

__device__ __forceinline__ float bf2f(unsigned short s) {
  unsigned int u = ((unsigned int)s) << 16;
  float f; __builtin_memcpy(&f, &u, 4); return f;
}
__device__ __forceinline__ unsigned short f2bf(float f) {
  unsigned int u; __builtin_memcpy(&u, &f, 4);
  u = u + 0x7FFFu + ((u >> 16) & 1u);   // round-to-nearest-even
  return (unsigned short)(u >> 16);
}

// async global->LDS, 16B per lane; lds dest is wave-uniform base + lane*16
__device__ __forceinline__ void gload_lds16(const unsigned short* g, unsigned short* l) {
  __builtin_amdgcn_global_load_lds(
      (const __attribute__((address_space(1))) unsigned int*)g,
      (__attribute__((address_space(3))) unsigned int*)l,
      16, 0, 0);
}

// ---------------- f32 -> bf16 convert (vectorized) ----------------
__global__ void k_cvt(const float* __restrict__ src, unsigned short* __restrict__ dst, int n4) {
  int i = blockIdx.x * 256 + threadIdx.x;
  if (i >= n4) return;
  const float4 v = ((const float4*)src)[i];
  ushort4 o;
  o.x = f2bf(v.x); o.y = f2bf(v.y); o.z = f2bf(v.z); o.w = f2bf(v.w);
  ((ushort4*)dst)[i] = o;
}

// ---------------- embedding gather -> bf16 ----------------
__global__ void k_embed(const int* __restrict__ tg, const float* __restrict__ em,
                        unsigned short* __restrict__ x0) {
  int idx = blockIdx.x * 256 + threadIdx.x;   // [0, B*U*H/4)
  int bu = idx >> 8;                          // H/4 = 256 chunks per row
  int kc = (idx & 255) << 2;
  int t = tg[bu];
  const float4 v = *(const float4*)&em[(long)t * H_ + kc];
  ushort4 o; o.x = f2bf(v.x); o.y = f2bf(v.y); o.z = f2bf(v.z); o.w = f2bf(v.w);
  *(ushort4*)&x0[bu * H_ + kc] = o;
}

// ---------------- bf16 MFMA GEMM (m97 structure):  C[M,N] = A[M,K] * W[N,K]^T + b1 + b2 ----------------
// M % 128 == 0, K % 32 == 0. Staging is UNMASKED: W must be allocated/padded to
// ceil(N/128)*128 rows. Epilogue stores are masked at N.
__global__ __launch_bounds__(256) void gemm_bt(
    const unsigned short* __restrict__ A, const unsigned short* __restrict__ W,
    const float* __restrict__ b1, const float* __restrict__ b2,
    float* __restrict__ C, int M, int N, int K)
{
  __shared__ unsigned short As[128 * 32];
  __shared__ unsigned short Bs[128 * 32];
  const int tid = threadIdx.x;
  const int n0 = blockIdx.x * 128, m0 = blockIdx.y * 128;
  const int lane = tid & 63, w = tid >> 6;
  const int wr = (w >> 1) * 64, wc = (w & 1) * 64;   // wave's 64x64 sub-tile
  const int lr = lane & 15, lk = (lane >> 4) * 8;
  f32x4 acc[4][4] = {};

  for (int k0 = 0; k0 < K; k0 += 32) {
#pragma unroll
    for (int s = 0; s < 2; ++s) {
      int idx = (w * 2 + s) * 64 + lane;     // 0..511 chunks of 16B
      int row = idx >> 2, c8 = (idx & 3) * 8;
      gload_lds16(&A[(long)(m0 + row) * K + k0 + c8], &As[(w * 2 + s) * 512]);
      gload_lds16(&W[(long)(n0 + row) * K + k0 + c8], &Bs[(w * 2 + s) * 512]);
    }
    __syncthreads();   // compiler emits vmcnt(0) drain before barrier
    bf16x8 aF[4], bF[4];
#pragma unroll
    for (int i = 0; i < 4; ++i) {
      aF[i] = *(const bf16x8*)&As[(wr + i * 16 + lr) * 32 + lk];
      bF[i] = *(const bf16x8*)&Bs[(wc + i * 16 + lr) * 32 + lk];
    }
#pragma unroll
    for (int i = 0; i < 4; ++i)
#pragma unroll
      for (int j = 0; j < 4; ++j)
        acc[i][j] = __builtin_amdgcn_mfma_f32_16x16x32_bf16(aF[i], bF[j], acc[i][j], 0, 0, 0);
    __syncthreads();
  }

  // epilogue: C/D layout col=lane&15, row=(lane>>4)*4+r
  const int lq = (lane >> 4) * 4;
#pragma unroll
  for (int j = 0; j < 4; ++j) {
    int col = n0 + wc + j * 16 + lr;
    if (col >= N) continue;
    float bb = 0.f;
    if (b1) bb += b1[col];
    if (b2) bb += b2[col];
#pragma unroll
    for (int i = 0; i < 4; ++i) {
      int rowg = m0 + wr + i * 16 + lq;
#pragma unroll
      for (int r = 0; r < 4; ++r)
        C[(long)(rowg + r) * N + col] = acc[i][j][r] + bb;
    }
  }
}

// ---------------- persistent LSTM layer kernel ----------------
// grid = 64 blocks x 256 threads. Block bid owns h-indices j in [bid*16, bid*16+16)
// i.e. gate-rows {g*1024 + bid*16 + q}. Thread (w = tid>>6, l = tid&63):
// row_local = l (g = l>>4, q = l&15), k-segment w (k in [w*256, w*256+256)).
// Whh segment held in VGPRs (32 x bf16x8). h exchanged via global f32 ping-pong +
// device-scope atomic spin barrier (counter pre-zeroed by host memset).
__global__ __launch_bounds__(256, 1) void lstm_seq(
    const float* __restrict__ xg,            // [B*U][4096] input proj + biases
    const unsigned short* __restrict__ Whh,  // [4096][1024] bf16 (this layer)
    unsigned short* __restrict__ xout,       // [B*U][1024] bf16 layer output
    float* __restrict__ hbuf,                // [2][B][1024] f32 ping-pong
    int* __restrict__ bar)                   // zeroed before launch
{
  __shared__ float hs[2][H_];        // staged h (both batches)
  __shared__ float xgs[128][64];     // xg slice: [b*64+u][l]
  __shared__ float part[4][64][2];   // k-segment partials
  __shared__ float gv[2][64];        // gate pre-activations

  const int tid = threadIdx.x, bid = blockIdx.x;
  const int w = tid >> 6, l = tid & 63;
  const int g = l >> 4, q = l & 15;
  const int row = g * 1024 + bid * 16 + q;
  const int kb = w * 256;

  // ---- load this thread's Whh segment into VGPRs (once) ----
  bf16x8 wreg[32];
#pragma unroll
  for (int it = 0; it < 32; ++it)
    wreg[it] = *(const bf16x8*)&Whh[(long)row * H_ + kb + it * 8];

  // ---- stage this block's xg slice into LDS (once) ----
#pragma unroll
  for (int rep = 0; rep < 8; ++rep) {
    int c = rep * 256 + tid;                 // 2048 float4 chunks
    int r2 = c >> 4, sub = c & 15;           // r2 = b*64+u
    int gg = sub >> 2, f4 = sub & 3;
    const float4 v = *(const float4*)&xg[(long)r2 * 4096 + gg * 1024 + bid * 16 + f4 * 4];
    *(float4*)&xgs[r2][gg * 16 + f4 * 4] = v;
  }
  __syncthreads();

  float creg = 0.f;                          // c-state for threads tid<32: (b=tid>>4, q=tid&15)

  for (int u = 0; u < U_; ++u) {
    float a00 = 0.f, a01 = 0.f, a02 = 0.f, a03 = 0.f;
    float a10 = 0.f, a11 = 0.f, a12 = 0.f, a13 = 0.f;
    if (u > 0) {
      // stage h (written last step, made visible by the barrier)
      const float* hsrc = hbuf + ((u & 1) ^ 1) * 2 * H_;
      *(float4*)&hs[0][tid * 4]  = *(const float4*)&hsrc[tid * 4];
      *(float4*)&hs[1][tid * 4]  = *(const float4*)&hsrc[H_ + tid * 4];
      __syncthreads();
#pragma unroll
      for (int it = 0; it < 32; ++it) {
        bf16x8 wv = wreg[it];
#pragma unroll
        for (int e = 0; e < 8; ++e) {
          float wf = bf2f((unsigned short)wv[e]);
          float h0 = hs[0][kb + it * 8 + e];
          float h1 = hs[1][kb + it * 8 + e];
          if ((e & 3) == 0)      { a00 += wf * h0; a10 += wf * h1; }
          else if ((e & 3) == 1) { a01 += wf * h0; a11 += wf * h1; }
          else if ((e & 3) == 2) { a02 += wf * h0; a12 += wf * h1; }
          else                   { a03 += wf * h0; a13 += wf * h1; }
        }
      }
    }
    part[w][l][0] = (a00 + a01) + (a02 + a03);
    part[w][l][1] = (a10 + a11) + (a12 + a13);
    __syncthreads();
    if (tid < 128) {
      int b = tid >> 6, ll = tid & 63;
      gv[b][ll] = part[0][ll][b] + part[1][ll][b] + part[2][ll][b] + part[3][ll][b]
                + xgs[b * 64 + u][ll];
    }
    __syncthreads();
    if (tid < 32) {
      int b = tid >> 4, qq = tid & 15;
      float gi = gv[b][qq], gf = gv[b][16 + qq], gc = gv[b][32 + qq], go = gv[b][48 + qq];
      float i_ = 1.f / (1.f + expf(-gi));
      float f_ = 1.f / (1.f + expf(-gf));
      float g_ = tanhf(gc);
      float o_ = 1.f / (1.f + expf(-go));
      creg = f_ * creg + i_ * g_;
      float h = o_ * tanhf(creg);
      int j = bid * 16 + qq;
      hbuf[(u & 1) * 2 * H_ + b * H_ + j] = h;
      xout[(b * U_ + u) * H_ + j] = f2bf(h);
    }
    if (u < U_ - 1) {
      __threadfence();                       // release h writes (agent scope)
      __syncthreads();
      if (tid == 0) {
        __hip_atomic_fetch_add(bar, 1, __ATOMIC_ACQ_REL, __HIP_MEMORY_SCOPE_AGENT);
        while (__hip_atomic_load(bar, __ATOMIC_ACQUIRE, __HIP_MEMORY_SCOPE_AGENT) < 64 * (u + 1))
          __builtin_amdgcn_s_sleep(2);
      }
      __syncthreads();
      // per-thread acquire so every thread's subsequent loads see remote h
      (void)__hip_atomic_load(bar, __ATOMIC_ACQUIRE, __HIP_MEMORY_SCOPE_AGENT);
    }
  }
}

// ---------------- joint = bf16(relu(enc_p[b,t,:] + prd_p[b,u,:])) ----------------
__global__ void k_joint(const float* __restrict__ ep, const float* __restrict__ pp,
                        unsigned short* __restrict__ jt)
{
  int idx = blockIdx.x * 256 + threadIdx.x;  // per float4; total 16384*256
  int m = idx >> 8;
  int kc = (idx & 255) << 2;
  int erow = m >> 6;                          // b*T + t
  int prow = (m >> 13) * U_ + (m & 63);       // b*U + u
  const float4 e = *(const float4*)&ep[erow * H_ + kc];
  const float4 p = *(const float4*)&pp[prow * H_ + kc];
  float4 s;
  s.x = fmaxf(e.x + p.x, 0.f); s.y = fmaxf(e.y + p.y, 0.f);
  s.z = fmaxf(e.z + p.z, 0.f); s.w = fmaxf(e.w + p.w, 0.f);
  ushort4 o; o.x = f2bf(s.x); o.y = f2bf(s.y); o.z = f2bf(s.z); o.w = f2bf(s.w);
  *(ushort4*)&jt[m * H_ + kc] = o;
}

extern "C" void kernel_launch(void* const* d_in, const int* in_sizes, int n_in,
                              void* d_out, int out_size, void* d_ws, size_t ws_size,
                              hipStream_t stream)
{
  const float* enc   = (const float*)d_in[0];
  const int*   tg    = (const int*)d_in[1];
  const float* em    = (const float*)d_in[2];
  const float* Wih   = (const float*)d_in[3];
  const float* Whh   = (const float*)d_in[4];
  const float* bih   = (const float*)d_in[5];
  const float* bhh   = (const float*)d_in[6];
  const float* encW  = (const float*)d_in[7];
  const float* encB  = (const float*)d_in[8];
  const float* prdW  = (const float*)d_in[9];
  const float* prdB  = (const float*)d_in[10];
  const float* outW  = (const float*)d_in[11];
  const float* outB  = (const float*)d_in[12];
  float* out = (float*)d_out;
  char* ws = (char*)d_ws;

  // workspace layout (bytes); outW_bf padded to 5120 rows for unmasked staging
  unsigned short* outW_bf = (unsigned short*)(ws + 0);         // 5120*1024*2 = 10,485,760
  unsigned short* Wih_bf  = (unsigned short*)(ws + 10485760);  // 2*4096*1024*2
  unsigned short* Whh_bf  = (unsigned short*)(ws + 27262976);  // 2*4096*1024*2
  unsigned short* encW_bf = (unsigned short*)(ws + 44040192);  // 1024*1024*2
  unsigned short* prdW_bf = (unsigned short*)(ws + 46137344);  // 1024*1024*2
  unsigned short* enc_bf  = (unsigned short*)(ws + 48234496);  // 256*1024*2
  unsigned short* x0_bf   = (unsigned short*)(ws + 48758784);  // 128*1024*2
  unsigned short* x1_bf   = (unsigned short*)(ws + 49020928);  // 128*1024*2
  unsigned short* x2_bf   = (unsigned short*)(ws + 49283072);  // 128*1024*2
  float* xg  = (float*)(ws + 49545216);                        // 128*4096*4 = 2,097,152
  float* hbuf = (float*)(ws + 51642368);                       // 2*2*1024*4 = 16,384
  int*   bar  = (int*)(ws + 51658752);                         // 256 B (both counters inside)
  unsigned short* jt = (unsigned short*)(ws + 51659008);       // 16384*1024*2 = 33,554,432
  // ep/pp overlap xg (xg is dead once both lstm_seq are done)
  float* ep = xg;                                              // 256*1024*4 = 1,048,576
  float* pp = (float*)(ws + 49545216 + 1048576);               // 128*1024*4

  // zero BOTH barrier counters: layer0 at bar+0, layer1 at bar+32 (byte 128) —
  // round-2 bug was bar+64 (byte 256), one past the memset range -> deadlock.
  hipMemsetAsync(bar, 0, 256, stream);

  // weight / activation conversions to bf16
  {
    int n4;
    n4 = (NO_ * H_) >> 2;        k_cvt<<<(n4 + 255) / 256, 256, 0, stream>>>(outW, outW_bf, n4);
    n4 = (2 * 4096 * H_) >> 2;   k_cvt<<<(n4 + 255) / 256, 256, 0, stream>>>(Wih, Wih_bf, n4);
    n4 = (2 * 4096 * H_) >> 2;   k_cvt<<<(n4 + 255) / 256, 256, 0, stream>>>(Whh, Whh_bf, n4);
    n4 = (H_ * H_) >> 2;         k_cvt<<<(n4 + 255) / 256, 256, 0, stream>>>(encW, encW_bf, n4);
    n4 = (H_ * H_) >> 2;         k_cvt<<<(n4 + 255) / 256, 256, 0, stream>>>(prdW, prdW_bf, n4);
    n4 = (B_ * T_ * H_) >> 2;    k_cvt<<<(n4 + 255) / 256, 256, 0, stream>>>(enc, enc_bf, n4);
  }
  k_embed<<<(B_ * U_ * H_ / 4) / 256, 256, 0, stream>>>(tg, em, x0_bf);

  // ---- LSTM layer 0 ----
  gemm_bt<<<dim3(32, 1), 256, 0, stream>>>(x0_bf, Wih_bf, bih, bhh, xg, B_ * U_, 4096, H_);
  lstm_seq<<<64, 256, 0, stream>>>(xg, Whh_bf, x1_bf, hbuf, bar);
  // ---- LSTM layer 1 ----
  gemm_bt<<<dim3(32, 1), 256, 0, stream>>>(x1_bf, Wih_bf + 4096 * H_, bih + 4096, bhh + 4096,
                                           xg, B_ * U_, 4096, H_);
  lstm_seq<<<64, 256, 0, stream>>>(xg, Whh_bf + 4096 * H_, x2_bf, hbuf, bar + 32);

  // ---- projections ----
  gemm_bt<<<dim3(8, 2), 256, 0, stream>>>(enc_bf, encW_bf, encB, nullptr, ep, B_ * T_, H_, H_);
  gemm_bt<<<dim3(8, 1), 256, 0, stream>>>(x2_bf, prdW_bf, prdB, nullptr, pp, B_ * U_, H_, H_);

  // ---- joint + logits ----
  k_joint<<<16384, 256, 0, stream>>>(ep, pp, jt);
  gemm_bt<<<dim3((NO_ + 127) / 128, B_ * T_ * U_ / 128), 256, 0, stream>>>(
      jt, outW_bf, outB, nullptr, out, B_ * T_ * U_, NO_, H_);
}

// Round 4
// 2062.382 us; speedup vs baseline: 1.3456x; 1.3383x over previous
//
#include <hip/hip_runtime.h>
#include <hip/hip_bf16.h>

#define B_ 2
#define T_ 128
#define U_ 64
#define H_ 1024
#define NO_ 5001

typedef __attribute__((ext_vector_type(8))) short bf16x8;
typedef __attribute__((ext_vector_type(4))) float f32x4;
typedef __attribute__((ext_vector_type(4))) unsigned int uint4v;

__device__ __forceinline__ float bf2f(unsigned short s) {
  unsigned int u = ((unsigned int)s) << 16;
  float f; __builtin_memcpy(&f, &u, 4); return f;
}
__device__ __forceinline__ unsigned short f2bf(float f) {
  unsigned int u; __builtin_memcpy(&u, &f, 4);
  u = u + 0x7FFFu + ((u >> 16) & 1u);   // round-to-nearest-even
  return (unsigned short)(u >> 16);
}

// async global->LDS, 16B per lane; lds dest is wave-uniform base + lane*16
__device__ __forceinline__ void gload_lds16(const unsigned short* g, unsigned short* l) {
  __builtin_amdgcn_global_load_lds(
      (const __attribute__((address_space(1))) unsigned int*)g,
      (__attribute__((address_space(3))) unsigned int*)l,
      16, 0, 0);
}

// ---------------- f32 -> bf16 convert (vectorized) ----------------
__global__ void k_cvt(const float* __restrict__ src, unsigned short* __restrict__ dst, int n4) {
  int i = blockIdx.x * 256 + threadIdx.x;
  if (i >= n4) return;
  const float4 v = ((const float4*)src)[i];
  ushort4 o;
  o.x = f2bf(v.x); o.y = f2bf(v.y); o.z = f2bf(v.z); o.w = f2bf(v.w);
  ((ushort4*)dst)[i] = o;
}

// ---------------- embedding gather -> bf16 ----------------
__global__ void k_embed(const int* __restrict__ tg, const float* __restrict__ em,
                        unsigned short* __restrict__ x0) {
  int idx = blockIdx.x * 256 + threadIdx.x;   // [0, B*U*H/4)
  int bu = idx >> 8;                          // H/4 = 256 chunks per row
  int kc = (idx & 255) << 2;
  int t = tg[bu];
  const float4 v = *(const float4*)&em[(long)t * H_ + kc];
  ushort4 o; o.x = f2bf(v.x); o.y = f2bf(v.y); o.z = f2bf(v.z); o.w = f2bf(v.w);
  *(ushort4*)&x0[bu * H_ + kc] = o;
}

// ---------------- bf16 MFMA GEMM (m97 structure):  C[M,N] = A[M,K] * W[N,K]^T + b1 + b2 ----------------
// M % 128 == 0, K % 32 == 0. Staging is UNMASKED: W must be allocated/padded to
// ceil(N/128)*128 rows. Epilogue stores are masked at N.
__global__ __launch_bounds__(256) void gemm_bt(
    const unsigned short* __restrict__ A, const unsigned short* __restrict__ W,
    const float* __restrict__ b1, const float* __restrict__ b2,
    float* __restrict__ C, int M, int N, int K)
{
  __shared__ unsigned short As[128 * 32];
  __shared__ unsigned short Bs[128 * 32];
  const int tid = threadIdx.x;
  const int n0 = blockIdx.x * 128, m0 = blockIdx.y * 128;
  const int lane = tid & 63, w = tid >> 6;
  const int wr = (w >> 1) * 64, wc = (w & 1) * 64;   // wave's 64x64 sub-tile
  const int lr = lane & 15, lk = (lane >> 4) * 8;
  f32x4 acc[4][4] = {};

  for (int k0 = 0; k0 < K; k0 += 32) {
#pragma unroll
    for (int s = 0; s < 2; ++s) {
      int idx = (w * 2 + s) * 64 + lane;     // 0..511 chunks of 16B
      int row = idx >> 2, c8 = (idx & 3) * 8;
      gload_lds16(&A[(long)(m0 + row) * K + k0 + c8], &As[(w * 2 + s) * 512]);
      gload_lds16(&W[(long)(n0 + row) * K + k0 + c8], &Bs[(w * 2 + s) * 512]);
    }
    __syncthreads();   // compiler emits vmcnt(0) drain before barrier
    bf16x8 aF[4], bF[4];
#pragma unroll
    for (int i = 0; i < 4; ++i) {
      aF[i] = *(const bf16x8*)&As[(wr + i * 16 + lr) * 32 + lk];
      bF[i] = *(const bf16x8*)&Bs[(wc + i * 16 + lr) * 32 + lk];
    }
#pragma unroll
    for (int i = 0; i < 4; ++i)
#pragma unroll
      for (int j = 0; j < 4; ++j)
        acc[i][j] = __builtin_amdgcn_mfma_f32_16x16x32_bf16(aF[i], bF[j], acc[i][j], 0, 0, 0);
    __syncthreads();
  }

  // epilogue: C/D layout col=lane&15, row=(lane>>4)*4+r
  const int lq = (lane >> 4) * 4;
#pragma unroll
  for (int j = 0; j < 4; ++j) {
    int col = n0 + wc + j * 16 + lr;
    if (col >= N) continue;
    float bb = 0.f;
    if (b1) bb += b1[col];
    if (b2) bb += b2[col];
#pragma unroll
    for (int i = 0; i < 4; ++i) {
      int rowg = m0 + wr + i * 16 + lq;
#pragma unroll
      for (int r = 0; r < 4; ++r)
        C[(long)(rowg + r) * N + col] = acc[i][j][r] + bb;
    }
  }
}

// ---------------- persistent LSTM layer kernel ----------------
// grid = 64 blocks x 256 threads. Block bid owns h-indices j in [bid*16, bid*16+16).
// Thread (w = tid>>6, l = tid&63): gate-row l (g = l>>4, q = l&15), k-segment w.
// Whh segment held in VGPRs (32 x bf16x8).
// SYNC REDESIGN (round-3 post-mortem): h exchanged via RELAXED agent-scope atomics
// (sc0/sc1 write-through stores, LLC-direct loads) — NO fences, NO acquire loads,
// so zero buffer_wbl2 / buffer_inv cache-maintenance ops. Ordering "h visible
// before arrival" is s_waitcnt vmcnt(0) on the storing wave (sc1 stores are at the
// coherence point when vmcnt retires). Counter is a monotonic relaxed fetch_add.
__global__ __launch_bounds__(256, 1) void lstm_seq(
    const float* __restrict__ xg,            // [B*U][4096] input proj + biases
    const unsigned short* __restrict__ Whh,  // [4096][1024] bf16 (this layer)
    unsigned short* __restrict__ xout,       // [B*U][1024] bf16 layer output
    float* __restrict__ hbuf,                // [2][B][1024] f32 ping-pong
    int* __restrict__ bar)                   // zeroed before launch
{
  __shared__ float hs[2][H_];        // staged h (both batches)
  __shared__ float xgs[128][64];     // xg slice: [b*64+u][l]
  __shared__ float part[4][64][2];   // k-segment partials
  __shared__ float gv[2][64];        // gate pre-activations

  const int tid = threadIdx.x, bid = blockIdx.x;
  const int w = tid >> 6, l = tid & 63;
  const int g = l >> 4, q = l & 15;
  const int row = g * 1024 + bid * 16 + q;
  const int kb = w * 256;

  // ---- load this thread's Whh segment into VGPRs (once) ----
  bf16x8 wreg[32];
#pragma unroll
  for (int it = 0; it < 32; ++it)
    wreg[it] = *(const bf16x8*)&Whh[(long)row * H_ + kb + it * 8];

  // ---- stage this block's xg slice into LDS (once) ----
#pragma unroll
  for (int rep = 0; rep < 8; ++rep) {
    int c = rep * 256 + tid;                 // 2048 float4 chunks
    int r2 = c >> 4, sub = c & 15;           // r2 = b*64+u
    int gg = sub >> 2, f4 = sub & 3;
    const float4 v = *(const float4*)&xg[(long)r2 * 4096 + gg * 1024 + bid * 16 + f4 * 4];
    *(float4*)&xgs[r2][gg * 16 + f4 * 4] = v;
  }
  __syncthreads();

  float creg = 0.f;                          // c-state for threads tid<32: (b=tid>>4, q=tid&15)

  for (int u = 0; u < U_; ++u) {
    float a00 = 0.f, a01 = 0.f, a02 = 0.f, a03 = 0.f;
    float a10 = 0.f, a11 = 0.f, a12 = 0.f, a13 = 0.f;
    if (u > 0) {
      // stage h: relaxed agent-scope loads go straight to the LLC (sc1),
      // bypassing any stale L1/L2 lines — no invalidate needed.
      const float* hsrc = hbuf + ((u & 1) ^ 1) * 2 * H_;
#pragma unroll
      for (int e = 0; e < 4; ++e) {
        hs[0][tid * 4 + e] = __hip_atomic_load(&hsrc[tid * 4 + e],
                                               __ATOMIC_RELAXED, __HIP_MEMORY_SCOPE_AGENT);
        hs[1][tid * 4 + e] = __hip_atomic_load(&hsrc[H_ + tid * 4 + e],
                                               __ATOMIC_RELAXED, __HIP_MEMORY_SCOPE_AGENT);
      }
      __syncthreads();
#pragma unroll
      for (int it = 0; it < 32; ++it) {
        bf16x8 wv = wreg[it];
#pragma unroll
        for (int e = 0; e < 8; ++e) {
          float wf = bf2f((unsigned short)wv[e]);
          float h0 = hs[0][kb + it * 8 + e];
          float h1 = hs[1][kb + it * 8 + e];
          if ((e & 3) == 0)      { a00 += wf * h0; a10 += wf * h1; }
          else if ((e & 3) == 1) { a01 += wf * h0; a11 += wf * h1; }
          else if ((e & 3) == 2) { a02 += wf * h0; a12 += wf * h1; }
          else                   { a03 += wf * h0; a13 += wf * h1; }
        }
      }
    }
    part[w][l][0] = (a00 + a01) + (a02 + a03);
    part[w][l][1] = (a10 + a11) + (a12 + a13);
    __syncthreads();
    if (tid < 128) {
      int b = tid >> 6, ll = tid & 63;
      gv[b][ll] = part[0][ll][b] + part[1][ll][b] + part[2][ll][b] + part[3][ll][b]
                + xgs[b * 64 + u][ll];
    }
    __syncthreads();
    if (tid < 32) {
      int b = tid >> 4, qq = tid & 15;
      float gi = gv[b][qq], gf = gv[b][16 + qq], gc = gv[b][32 + qq], go = gv[b][48 + qq];
      float i_ = 1.f / (1.f + expf(-gi));
      float f_ = 1.f / (1.f + expf(-gf));
      float g_ = tanhf(gc);
      float o_ = 1.f / (1.f + expf(-go));
      creg = f_ * creg + i_ * g_;
      float h = o_ * tanhf(creg);
      int j = bid * 16 + qq;
      // write-through store to the LLC (coherent point) — no fence needed
      __hip_atomic_store(&hbuf[(u & 1) * 2 * H_ + b * H_ + j], h,
                         __ATOMIC_RELAXED, __HIP_MEMORY_SCOPE_AGENT);
      xout[(b * U_ + u) * H_ + j] = f2bf(h);
    }
    if (u < U_ - 1) {
      // h stores (wave 0) must be at the LLC before the arrival is visible:
      // sc1 stores are globally visible once vmcnt retires.
      asm volatile("s_waitcnt vmcnt(0)" ::: "memory");
      __syncthreads();
      if (tid == 0) {
        __hip_atomic_fetch_add(bar, 1, __ATOMIC_RELAXED, __HIP_MEMORY_SCOPE_AGENT);
        while (__hip_atomic_load(bar, __ATOMIC_RELAXED, __HIP_MEMORY_SCOPE_AGENT) < 64 * (u + 1))
          __builtin_amdgcn_s_sleep(4);
      }
      __syncthreads();
    }
  }
}

// ---------------- joint = bf16(relu(enc_p[b,t,:] + prd_p[b,u,:])) ----------------
__global__ void k_joint(const float* __restrict__ ep, const float* __restrict__ pp,
                        unsigned short* __restrict__ jt)
{
  int idx = blockIdx.x * 256 + threadIdx.x;  // per float4; total 16384*256
  int m = idx >> 8;
  int kc = (idx & 255) << 2;
  int erow = m >> 6;                          // b*T + t
  int prow = (m >> 13) * U_ + (m & 63);       // b*U + u
  const float4 e = *(const float4*)&ep[erow * H_ + kc];
  const float4 p = *(const float4*)&pp[prow * H_ + kc];
  float4 s;
  s.x = fmaxf(e.x + p.x, 0.f); s.y = fmaxf(e.y + p.y, 0.f);
  s.z = fmaxf(e.z + p.z, 0.f); s.w = fmaxf(e.w + p.w, 0.f);
  ushort4 o; o.x = f2bf(s.x); o.y = f2bf(s.y); o.z = f2bf(s.z); o.w = f2bf(s.w);
  *(ushort4*)&jt[m * H_ + kc] = o;
}

extern "C" void kernel_launch(void* const* d_in, const int* in_sizes, int n_in,
                              void* d_out, int out_size, void* d_ws, size_t ws_size,
                              hipStream_t stream)
{
  const float* enc   = (const float*)d_in[0];
  const int*   tg    = (const int*)d_in[1];
  const float* em    = (const float*)d_in[2];
  const float* Wih   = (const float*)d_in[3];
  const float* Whh   = (const float*)d_in[4];
  const float* bih   = (const float*)d_in[5];
  const float* bhh   = (const float*)d_in[6];
  const float* encW  = (const float*)d_in[7];
  const float* encB  = (const float*)d_in[8];
  const float* prdW  = (const float*)d_in[9];
  const float* prdB  = (const float*)d_in[10];
  const float* outW  = (const float*)d_in[11];
  const float* outB  = (const float*)d_in[12];
  float* out = (float*)d_out;
  char* ws = (char*)d_ws;

  // workspace layout (bytes); outW_bf padded to 5120 rows for unmasked staging
  unsigned short* outW_bf = (unsigned short*)(ws + 0);         // 5120*1024*2 = 10,485,760
  unsigned short* Wih_bf  = (unsigned short*)(ws + 10485760);  // 2*4096*1024*2
  unsigned short* Whh_bf  = (unsigned short*)(ws + 27262976);  // 2*4096*1024*2
  unsigned short* encW_bf = (unsigned short*)(ws + 44040192);  // 1024*1024*2
  unsigned short* prdW_bf = (unsigned short*)(ws + 46137344);  // 1024*1024*2
  unsigned short* enc_bf  = (unsigned short*)(ws + 48234496);  // 256*1024*2
  unsigned short* x0_bf   = (unsigned short*)(ws + 48758784);  // 128*1024*2
  unsigned short* x1_bf   = (unsigned short*)(ws + 49020928);  // 128*1024*2
  unsigned short* x2_bf   = (unsigned short*)(ws + 49283072);  // 128*1024*2
  float* xg  = (float*)(ws + 49545216);                        // 128*4096*4 = 2,097,152
  float* hbuf = (float*)(ws + 51642368);                       // 2*2*1024*4 = 16,384
  int*   bar  = (int*)(ws + 51658752);                         // 256 B (both counters inside)
  unsigned short* jt = (unsigned short*)(ws + 51659008);       // 16384*1024*2 = 33,554,432
  // ep/pp overlap xg (xg is dead once both lstm_seq are done)
  float* ep = xg;                                              // 256*1024*4 = 1,048,576
  float* pp = (float*)(ws + 49545216 + 1048576);               // 128*1024*4

  // zero BOTH barrier counters: layer0 at bar+0, layer1 at bar+32 (byte 128)
  hipMemsetAsync(bar, 0, 256, stream);

  // weight / activation conversions to bf16
  {
    int n4;
    n4 = (NO_ * H_) >> 2;        k_cvt<<<(n4 + 255) / 256, 256, 0, stream>>>(outW, outW_bf, n4);
    n4 = (2 * 4096 * H_) >> 2;   k_cvt<<<(n4 + 255) / 256, 256, 0, stream>>>(Wih, Wih_bf, n4);
    n4 = (2 * 4096 * H_) >> 2;   k_cvt<<<(n4 + 255) / 256, 256, 0, stream>>>(Whh, Whh_bf, n4);
    n4 = (H_ * H_) >> 2;         k_cvt<<<(n4 + 255) / 256, 256, 0, stream>>>(encW, encW_bf, n4);
    n4 = (H_ * H_) >> 2;         k_cvt<<<(n4 + 255) / 256, 256, 0, stream>>>(prdW, prdW_bf, n4);
    n4 = (B_ * T_ * H_) >> 2;    k_cvt<<<(n4 + 255) / 256, 256, 0, stream>>>(enc, enc_bf, n4);
  }
  k_embed<<<(B_ * U_ * H_ / 4) / 256, 256, 0, stream>>>(tg, em, x0_bf);

  // ---- LSTM layer 0 ----
  gemm_bt<<<dim3(32, 1), 256, 0, stream>>>(x0_bf, Wih_bf, bih, bhh, xg, B_ * U_, 4096, H_);
  lstm_seq<<<64, 256, 0, stream>>>(xg, Whh_bf, x1_bf, hbuf, bar);
  // ---- LSTM layer 1 ----
  gemm_bt<<<dim3(32, 1), 256, 0, stream>>>(x1_bf, Wih_bf + 4096 * H_, bih + 4096, bhh + 4096,
                                           xg, B_ * U_, 4096, H_);
  lstm_seq<<<64, 256, 0, stream>>>(xg, Whh_bf + 4096 * H_, x2_bf, hbuf, bar + 32);

  // ---- projections ----
  gemm_bt<<<dim3(8, 2), 256, 0, stream>>>(enc_bf, encW_bf, encB, nullptr, ep, B_ * T_, H_, H_);
  gemm_bt<<<dim3(8, 1), 256, 0, stream>>>(x2_bf, prdW_bf, prdB, nullptr, pp, B_ * U_, H_, H_);

  // ---- joint + logits ----
  k_joint<<<16384, 256, 0, stream>>>(ep, pp, jt);
  gemm_bt<<<dim3((NO_ + 127) / 128, B_ * T_ * U_ / 128), 256, 0, stream>>>(
      jt, outW_bf, outB, nullptr, out, B_ * T_ * U_, NO_, H_);
}

// Round 5
// 1936.404 us; speedup vs baseline: 1.4331x; 1.0651x over previous
//
#include <hip/hip_runtime.h>
#include <hip/hip_bf16.h>

#define B_ 2
#define T_ 128
#define U_ 64
#define H_ 1024
#define NO_ 5001

typedef __attribute__((ext_vector_type(8))) short bf16x8;
typedef __attribute__((ext_vector_type(4))) float f32x4;
typedef __attribute__((ext_vector_type(4))) unsigned int uint4v;

__device__ __forceinline__ float bf2f(unsigned short s) {
  unsigned int u = ((unsigned int)s) << 16;
  float f; __builtin_memcpy(&f, &u, 4); return f;
}
__device__ __forceinline__ unsigned short f2bf(float f) {
  unsigned int u; __builtin_memcpy(&u, &f, 4);
  u = u + 0x7FFFu + ((u >> 16) & 1u);   // round-to-nearest-even
  return (unsigned short)(u >> 16);
}

// async global->LDS, 16B per lane; lds dest is wave-uniform base + lane*16
__device__ __forceinline__ void gload_lds16(const unsigned short* g, unsigned short* l) {
  __builtin_amdgcn_global_load_lds(
      (const __attribute__((address_space(1))) unsigned int*)g,
      (__attribute__((address_space(3))) unsigned int*)l,
      16, 0, 0);
}

// ---------------- f32 -> bf16 convert (vectorized) ----------------
__global__ void k_cvt(const float* __restrict__ src, unsigned short* __restrict__ dst, int n4) {
  int i = blockIdx.x * 256 + threadIdx.x;
  if (i >= n4) return;
  const float4 v = ((const float4*)src)[i];
  ushort4 o;
  o.x = f2bf(v.x); o.y = f2bf(v.y); o.z = f2bf(v.z); o.w = f2bf(v.w);
  ((ushort4*)dst)[i] = o;
}

// ---------------- embedding gather -> bf16 ----------------
__global__ void k_embed(const int* __restrict__ tg, const float* __restrict__ em,
                        unsigned short* __restrict__ x0) {
  int idx = blockIdx.x * 256 + threadIdx.x;   // [0, B*U*H/4)
  int bu = idx >> 8;                          // H/4 = 256 chunks per row
  int kc = (idx & 255) << 2;
  int t = tg[bu];
  const float4 v = *(const float4*)&em[(long)t * H_ + kc];
  ushort4 o; o.x = f2bf(v.x); o.y = f2bf(v.y); o.z = f2bf(v.z); o.w = f2bf(v.w);
  *(ushort4*)&x0[bu * H_ + kc] = o;
}

// ---------------- bf16 MFMA GEMM (m97 structure):  C[M,N] = A[M,K] * W[N,K]^T + b1 + b2 ----------------
// M % 128 == 0, K % 32 == 0. Staging is UNMASKED: W must be allocated/padded to
// ceil(N/128)*128 rows. Epilogue stores are masked at N.
__global__ __launch_bounds__(256) void gemm_bt(
    const unsigned short* __restrict__ A, const unsigned short* __restrict__ W,
    const float* __restrict__ b1, const float* __restrict__ b2,
    float* __restrict__ C, int M, int N, int K)
{
  __shared__ unsigned short As[128 * 32];
  __shared__ unsigned short Bs[128 * 32];
  const int tid = threadIdx.x;
  const int n0 = blockIdx.x * 128, m0 = blockIdx.y * 128;
  const int lane = tid & 63, w = tid >> 6;
  const int wr = (w >> 1) * 64, wc = (w & 1) * 64;   // wave's 64x64 sub-tile
  const int lr = lane & 15, lk = (lane >> 4) * 8;
  f32x4 acc[4][4] = {};

  for (int k0 = 0; k0 < K; k0 += 32) {
#pragma unroll
    for (int s = 0; s < 2; ++s) {
      int idx = (w * 2 + s) * 64 + lane;     // 0..511 chunks of 16B
      int row = idx >> 2, c8 = (idx & 3) * 8;
      gload_lds16(&A[(long)(m0 + row) * K + k0 + c8], &As[(w * 2 + s) * 512]);
      gload_lds16(&W[(long)(n0 + row) * K + k0 + c8], &Bs[(w * 2 + s) * 512]);
    }
    __syncthreads();   // compiler emits vmcnt(0) drain before barrier
    bf16x8 aF[4], bF[4];
#pragma unroll
    for (int i = 0; i < 4; ++i) {
      aF[i] = *(const bf16x8*)&As[(wr + i * 16 + lr) * 32 + lk];
      bF[i] = *(const bf16x8*)&Bs[(wc + i * 16 + lr) * 32 + lk];
    }
#pragma unroll
    for (int i = 0; i < 4; ++i)
#pragma unroll
      for (int j = 0; j < 4; ++j)
        acc[i][j] = __builtin_amdgcn_mfma_f32_16x16x32_bf16(aF[i], bF[j], acc[i][j], 0, 0, 0);
    __syncthreads();
  }

  // epilogue: C/D layout col=lane&15, row=(lane>>4)*4+r
  const int lq = (lane >> 4) * 4;
#pragma unroll
  for (int j = 0; j < 4; ++j) {
    int col = n0 + wc + j * 16 + lr;
    if (col >= N) continue;
    float bb = 0.f;
    if (b1) bb += b1[col];
    if (b2) bb += b2[col];
#pragma unroll
    for (int i = 0; i < 4; ++i) {
      int rowg = m0 + wr + i * 16 + lq;
#pragma unroll
      for (int r = 0; r < 4; ++r)
        C[(long)(rowg + r) * N + col] = acc[i][j][r] + bb;
    }
  }
}

// ---------------- persistent LSTM layer kernel ----------------
// grid = 64 blocks x 256 threads. Block bid owns h-indices j in [bid*16, bid*16+16).
// Thread (w = tid>>6, l = tid&63): gate-row l (g = l>>4, q = l&15), k-segment w.
// Whh segment held in VGPRs (32 x bf16x8).
// BARRIER REDESIGN (round-4 post-mortem): the single fetch_add counter serialized
// 64 RMWs on one LLC line (~13 us/step). Now: per-block arrival FLAGS, one per
// 64B cache line (parallel sc1 stores, no RMW), and each wave polls all 64 flags
// with ONE 64-lane vector load + __all(). h stores ordered before the flag store
// by wave-local s_waitcnt vmcnt(0). All data moves via relaxed agent-scope
// atomics (LLC-direct, no cache-maintenance ops).
__global__ __launch_bounds__(256, 1) void lstm_seq(
    const float* __restrict__ xg,            // [B*U][4096] input proj + biases
    const unsigned short* __restrict__ Whh,  // [4096][1024] bf16 (this layer)
    unsigned short* __restrict__ xout,       // [B*U][1024] bf16 layer output
    float* __restrict__ hbuf,                // [2][B][1024] f32 ping-pong
    int* __restrict__ flags)                 // [64] ints, 64B apart; zeroed before launch
{
  __shared__ float hs[2][H_];        // staged h (both batches)
  __shared__ float xgs[128][64];     // xg slice: [b*64+u][l]
  __shared__ float part[4][64][2];   // k-segment partials
  __shared__ float gv[2][64];        // gate pre-activations

  const int tid = threadIdx.x, bid = blockIdx.x;
  const int w = tid >> 6, l = tid & 63;
  const int g = l >> 4, q = l & 15;
  const int row = g * 1024 + bid * 16 + q;
  const int kb = w * 256;

  // ---- load this thread's Whh segment into VGPRs (once) ----
  bf16x8 wreg[32];
#pragma unroll
  for (int it = 0; it < 32; ++it)
    wreg[it] = *(const bf16x8*)&Whh[(long)row * H_ + kb + it * 8];

  // ---- stage this block's xg slice into LDS (once) ----
#pragma unroll
  for (int rep = 0; rep < 8; ++rep) {
    int c = rep * 256 + tid;                 // 2048 float4 chunks
    int r2 = c >> 4, sub = c & 15;           // r2 = b*64+u
    int gg = sub >> 2, f4 = sub & 3;
    const float4 v = *(const float4*)&xg[(long)r2 * 4096 + gg * 1024 + bid * 16 + f4 * 4];
    *(float4*)&xgs[r2][gg * 16 + f4 * 4] = v;
  }
  __syncthreads();

  float creg = 0.f;                          // c-state for threads tid<32: (b=tid>>4, q=tid&15)

  for (int u = 0; u < U_; ++u) {
    float a00 = 0.f, a01 = 0.f, a02 = 0.f, a03 = 0.f;
    float a10 = 0.f, a11 = 0.f, a12 = 0.f, a13 = 0.f;
    if (u > 0) {
      // stage h: relaxed agent-scope loads go straight to the LLC (sc1)
      const float* hsrc = hbuf + ((u & 1) ^ 1) * 2 * H_;
#pragma unroll
      for (int e = 0; e < 4; ++e) {
        hs[0][tid * 4 + e] = __hip_atomic_load(&hsrc[tid * 4 + e],
                                               __ATOMIC_RELAXED, __HIP_MEMORY_SCOPE_AGENT);
        hs[1][tid * 4 + e] = __hip_atomic_load(&hsrc[H_ + tid * 4 + e],
                                               __ATOMIC_RELAXED, __HIP_MEMORY_SCOPE_AGENT);
      }
      __syncthreads();
#pragma unroll
      for (int it = 0; it < 32; ++it) {
        bf16x8 wv = wreg[it];
#pragma unroll
        for (int e = 0; e < 8; ++e) {
          float wf = bf2f((unsigned short)wv[e]);
          float h0 = hs[0][kb + it * 8 + e];
          float h1 = hs[1][kb + it * 8 + e];
          if ((e & 3) == 0)      { a00 += wf * h0; a10 += wf * h1; }
          else if ((e & 3) == 1) { a01 += wf * h0; a11 += wf * h1; }
          else if ((e & 3) == 2) { a02 += wf * h0; a12 += wf * h1; }
          else                   { a03 += wf * h0; a13 += wf * h1; }
        }
      }
    }
    part[w][l][0] = (a00 + a01) + (a02 + a03);
    part[w][l][1] = (a10 + a11) + (a12 + a13);
    __syncthreads();
    if (tid < 128) {
      int b = tid >> 6, ll = tid & 63;
      gv[b][ll] = part[0][ll][b] + part[1][ll][b] + part[2][ll][b] + part[3][ll][b]
                + xgs[b * 64 + u][ll];
    }
    __syncthreads();
    if (tid < 32) {
      int b = tid >> 4, qq = tid & 15;
      float gi = gv[b][qq], gf = gv[b][16 + qq], gc = gv[b][32 + qq], go = gv[b][48 + qq];
      float i_ = 1.f / (1.f + expf(-gi));
      float f_ = 1.f / (1.f + expf(-gf));
      float g_ = tanhf(gc);
      float o_ = 1.f / (1.f + expf(-go));
      creg = f_ * creg + i_ * g_;
      float h = o_ * tanhf(creg);
      int j = bid * 16 + qq;
      // write-through store to the LLC (coherent point)
      __hip_atomic_store(&hbuf[(u & 1) * 2 * H_ + b * H_ + j], h,
                         __ATOMIC_RELAXED, __HIP_MEMORY_SCOPE_AGENT);
      xout[(b * U_ + u) * H_ + j] = f2bf(h);
    }
    if (u < U_ - 1) {
      // arrival: wave 0 (the h-storing wave) drains vmem, then sets this
      // block's flag on its private cache line — no RMW, parallel across blocks
      if (w == 0) {
        asm volatile("s_waitcnt vmcnt(0)" ::: "memory");
        if (tid == 0)
          __hip_atomic_store(&flags[bid * 16], u + 1,
                             __ATOMIC_RELAXED, __HIP_MEMORY_SCOPE_AGENT);
      }
      // wait: each wave gathers all 64 flags with one 64-lane load
      int fv;
      do {
        fv = __hip_atomic_load(&flags[l * 16], __ATOMIC_RELAXED, __HIP_MEMORY_SCOPE_AGENT);
      } while (!__all(fv > u));
      // no __syncthreads needed: every wave independently saw all arrivals,
      // and all intra-block LDS orderings are covered by the three syncs above
    }
  }
}

// ---------------- joint = bf16(relu(enc_p[b,t,:] + prd_p[b,u,:])) ----------------
__global__ void k_joint(const float* __restrict__ ep, const float* __restrict__ pp,
                        unsigned short* __restrict__ jt)
{
  int idx = blockIdx.x * 256 + threadIdx.x;  // per float4; total 16384*256
  int m = idx >> 8;
  int kc = (idx & 255) << 2;
  int erow = m >> 6;                          // b*T + t
  int prow = (m >> 13) * U_ + (m & 63);       // b*U + u
  const float4 e = *(const float4*)&ep[erow * H_ + kc];
  const float4 p = *(const float4*)&pp[prow * H_ + kc];
  float4 s;
  s.x = fmaxf(e.x + p.x, 0.f); s.y = fmaxf(e.y + p.y, 0.f);
  s.z = fmaxf(e.z + p.z, 0.f); s.w = fmaxf(e.w + p.w, 0.f);
  ushort4 o; o.x = f2bf(s.x); o.y = f2bf(s.y); o.z = f2bf(s.z); o.w = f2bf(s.w);
  *(ushort4*)&jt[m * H_ + kc] = o;
}

extern "C" void kernel_launch(void* const* d_in, const int* in_sizes, int n_in,
                              void* d_out, int out_size, void* d_ws, size_t ws_size,
                              hipStream_t stream)
{
  const float* enc   = (const float*)d_in[0];
  const int*   tg    = (const int*)d_in[1];
  const float* em    = (const float*)d_in[2];
  const float* Wih   = (const float*)d_in[3];
  const float* Whh   = (const float*)d_in[4];
  const float* bih   = (const float*)d_in[5];
  const float* bhh   = (const float*)d_in[6];
  const float* encW  = (const float*)d_in[7];
  const float* encB  = (const float*)d_in[8];
  const float* prdW  = (const float*)d_in[9];
  const float* prdB  = (const float*)d_in[10];
  const float* outW  = (const float*)d_in[11];
  const float* outB  = (const float*)d_in[12];
  float* out = (float*)d_out;
  char* ws = (char*)d_ws;

  // workspace layout (bytes); outW_bf padded to 5120 rows for unmasked staging
  unsigned short* outW_bf = (unsigned short*)(ws + 0);         // 5120*1024*2 = 10,485,760
  unsigned short* Wih_bf  = (unsigned short*)(ws + 10485760);  // 2*4096*1024*2
  unsigned short* Whh_bf  = (unsigned short*)(ws + 27262976);  // 2*4096*1024*2
  unsigned short* encW_bf = (unsigned short*)(ws + 44040192);  // 1024*1024*2
  unsigned short* prdW_bf = (unsigned short*)(ws + 46137344);  // 1024*1024*2
  unsigned short* enc_bf  = (unsigned short*)(ws + 48234496);  // 256*1024*2
  unsigned short* x0_bf   = (unsigned short*)(ws + 48758784);  // 128*1024*2
  unsigned short* x1_bf   = (unsigned short*)(ws + 49020928);  // 128*1024*2
  unsigned short* x2_bf   = (unsigned short*)(ws + 49283072);  // 128*1024*2
  float* xg  = (float*)(ws + 49545216);                        // 128*4096*4 = 2,097,152
  float* hbuf = (float*)(ws + 51642368);                       // 2*2*1024*4 = 16,384
  unsigned short* jt = (unsigned short*)(ws + 51659008);       // 16384*1024*2 -> ends 85,213,440
  int* flags0 = (int*)(ws + 85213440);                         // 64 flags x 64B = 4096
  int* flags1 = (int*)(ws + 85217536);                         // 64 flags x 64B = 4096
  // (round-1 layout peaked at 86.55 MB, so ws_size >= 85,221,632 is available)
  // ep/pp overlap xg (xg is dead once both lstm_seq are done)
  float* ep = xg;                                              // 256*1024*4 = 1,048,576
  float* pp = (float*)(ws + 49545216 + 1048576);               // 128*1024*4

  // zero both layers' arrival flags
  hipMemsetAsync(flags0, 0, 8192, stream);

  // weight / activation conversions to bf16
  {
    int n4;
    n4 = (NO_ * H_) >> 2;        k_cvt<<<(n4 + 255) / 256, 256, 0, stream>>>(outW, outW_bf, n4);
    n4 = (2 * 4096 * H_) >> 2;   k_cvt<<<(n4 + 255) / 256, 256, 0, stream>>>(Wih, Wih_bf, n4);
    n4 = (2 * 4096 * H_) >> 2;   k_cvt<<<(n4 + 255) / 256, 256, 0, stream>>>(Whh, Whh_bf, n4);
    n4 = (H_ * H_) >> 2;         k_cvt<<<(n4 + 255) / 256, 256, 0, stream>>>(encW, encW_bf, n4);
    n4 = (H_ * H_) >> 2;         k_cvt<<<(n4 + 255) / 256, 256, 0, stream>>>(prdW, prdW_bf, n4);
    n4 = (B_ * T_ * H_) >> 2;    k_cvt<<<(n4 + 255) / 256, 256, 0, stream>>>(enc, enc_bf, n4);
  }
  k_embed<<<(B_ * U_ * H_ / 4) / 256, 256, 0, stream>>>(tg, em, x0_bf);

  // ---- LSTM layer 0 ----
  gemm_bt<<<dim3(32, 1), 256, 0, stream>>>(x0_bf, Wih_bf, bih, bhh, xg, B_ * U_, 4096, H_);
  lstm_seq<<<64, 256, 0, stream>>>(xg, Whh_bf, x1_bf, hbuf, flags0);
  // ---- LSTM layer 1 ----
  gemm_bt<<<dim3(32, 1), 256, 0, stream>>>(x1_bf, Wih_bf + 4096 * H_, bih + 4096, bhh + 4096,
                                           xg, B_ * U_, 4096, H_);
  lstm_seq<<<64, 256, 0, stream>>>(xg, Whh_bf + 4096 * H_, x2_bf, hbuf, flags1);

  // ---- projections ----
  gemm_bt<<<dim3(8, 2), 256, 0, stream>>>(enc_bf, encW_bf, encB, nullptr, ep, B_ * T_, H_, H_);
  gemm_bt<<<dim3(8, 1), 256, 0, stream>>>(x2_bf, prdW_bf, prdB, nullptr, pp, B_ * U_, H_, H_);

  // ---- joint + logits ----
  k_joint<<<16384, 256, 0, stream>>>(ep, pp, jt);
  gemm_bt<<<dim3((NO_ + 127) / 128, B_ * T_ * U_ / 128), 256, 0, stream>>>(
      jt, outW_bf, outB, nullptr, out, B_ * T_ * U_, NO_, H_);
}

// Round 6
// 987.816 us; speedup vs baseline: 2.8093x; 1.9603x over previous
//
#include <hip/hip_runtime.h>
#include <hip/hip_bf16.h>

#define B_ 2
#define T_ 128
#define U_ 64
#define H_ 1024
#define NO_ 5001

typedef __attribute__((ext_vector_type(8))) short bf16x8;
typedef __attribute__((ext_vector_type(4))) float f32x4;
typedef __attribute__((ext_vector_type(4))) unsigned int uint4v;

__device__ __forceinline__ float bf2f(unsigned short s) {
  unsigned int u = ((unsigned int)s) << 16;
  float f; __builtin_memcpy(&f, &u, 4); return f;
}
__device__ __forceinline__ unsigned short f2bf(float f) {
  unsigned int u; __builtin_memcpy(&u, &f, 4);
  u = u + 0x7FFFu + ((u >> 16) & 1u);   // round-to-nearest-even
  return (unsigned short)(u >> 16);
}

// async global->LDS, 16B per lane; lds dest is wave-uniform base + lane*16
__device__ __forceinline__ void gload_lds16(const unsigned short* g, unsigned short* l) {
  __builtin_amdgcn_global_load_lds(
      (const __attribute__((address_space(1))) unsigned int*)g,
      (__attribute__((address_space(3))) unsigned int*)l,
      16, 0, 0);
}

// ---------------- f32 -> bf16 convert (vectorized) ----------------
__global__ void k_cvt(const float* __restrict__ src, unsigned short* __restrict__ dst, int n4) {
  int i = blockIdx.x * 256 + threadIdx.x;
  if (i >= n4) return;
  const float4 v = ((const float4*)src)[i];
  ushort4 o;
  o.x = f2bf(v.x); o.y = f2bf(v.y); o.z = f2bf(v.z); o.w = f2bf(v.w);
  ((ushort4*)dst)[i] = o;
}

// ---------------- embedding gather -> bf16 ----------------
__global__ void k_embed(const int* __restrict__ tg, const float* __restrict__ em,
                        unsigned short* __restrict__ x0) {
  int idx = blockIdx.x * 256 + threadIdx.x;   // [0, B*U*H/4)
  int bu = idx >> 8;                          // H/4 = 256 chunks per row
  int kc = (idx & 255) << 2;
  int t = tg[bu];
  const float4 v = *(const float4*)&em[(long)t * H_ + kc];
  ushort4 o; o.x = f2bf(v.x); o.y = f2bf(v.y); o.z = f2bf(v.z); o.w = f2bf(v.w);
  *(ushort4*)&x0[bu * H_ + kc] = o;
}

// ---------------- bf16 MFMA GEMM (m97 structure):  C[M,N] = A[M,K] * W[N,K]^T + b1 + b2 ----------------
// M % 128 == 0, K % 32 == 0. Staging is UNMASKED: W must be allocated/padded to
// ceil(N/128)*128 rows. Epilogue stores are masked at N.
__global__ __launch_bounds__(256) void gemm_bt(
    const unsigned short* __restrict__ A, const unsigned short* __restrict__ W,
    const float* __restrict__ b1, const float* __restrict__ b2,
    float* __restrict__ C, int M, int N, int K)
{
  __shared__ unsigned short As[128 * 32];
  __shared__ unsigned short Bs[128 * 32];
  const int tid = threadIdx.x;
  const int n0 = blockIdx.x * 128, m0 = blockIdx.y * 128;
  const int lane = tid & 63, w = tid >> 6;
  const int wr = (w >> 1) * 64, wc = (w & 1) * 64;   // wave's 64x64 sub-tile
  const int lr = lane & 15, lk = (lane >> 4) * 8;
  f32x4 acc[4][4] = {};

  for (int k0 = 0; k0 < K; k0 += 32) {
#pragma unroll
    for (int s = 0; s < 2; ++s) {
      int idx = (w * 2 + s) * 64 + lane;     // 0..511 chunks of 16B
      int row = idx >> 2, c8 = (idx & 3) * 8;
      gload_lds16(&A[(long)(m0 + row) * K + k0 + c8], &As[(w * 2 + s) * 512]);
      gload_lds16(&W[(long)(n0 + row) * K + k0 + c8], &Bs[(w * 2 + s) * 512]);
    }
    __syncthreads();   // compiler emits vmcnt(0) drain before barrier
    bf16x8 aF[4], bF[4];
#pragma unroll
    for (int i = 0; i < 4; ++i) {
      aF[i] = *(const bf16x8*)&As[(wr + i * 16 + lr) * 32 + lk];
      bF[i] = *(const bf16x8*)&Bs[(wc + i * 16 + lr) * 32 + lk];
    }
#pragma unroll
    for (int i = 0; i < 4; ++i)
#pragma unroll
      for (int j = 0; j < 4; ++j)
        acc[i][j] = __builtin_amdgcn_mfma_f32_16x16x32_bf16(aF[i], bF[j], acc[i][j], 0, 0, 0);
    __syncthreads();
  }

  // epilogue: C/D layout col=lane&15, row=(lane>>4)*4+r
  const int lq = (lane >> 4) * 4;
#pragma unroll
  for (int j = 0; j < 4; ++j) {
    int col = n0 + wc + j * 16 + lr;
    if (col >= N) continue;
    float bb = 0.f;
    if (b1) bb += b1[col];
    if (b2) bb += b2[col];
#pragma unroll
    for (int i = 0; i < 4; ++i) {
      int rowg = m0 + wr + i * 16 + lq;
#pragma unroll
      for (int r = 0; r < 4; ++r)
        C[(long)(rowg + r) * N + col] = acc[i][j][r] + bb;
    }
  }
}

// ---------------- persistent LSTM layer kernel ----------------
// grid = 64 blocks x 256 threads. Block bid owns h-indices j in [bid*16, bid*16+16).
// Thread (w = tid>>6, l = tid&63): gate-row l (g = l>>4, q = l&15), k-segment w.
// Whh segment held in VGPRs (32 x bf16x8).
// SYNC REDESIGN (round-5 post-mortem): TAG-IN-DATA. h in (-1,1) is transmitted as
// h + 4*step; the value itself is the arrival flag (threshold 4*step-2 excludes
// zeros, 0xAA poison, and all earlier tags). No flags, no fences, no vmcnt drains:
// producer = one sc1 write-through store; consumer = poll exactly the 2 float4s it
// stages until all 8 components pass, untag, LDS. 2-deep ping-pong is WAR-safe
// (tag u+2 can only be written after every block consumed tag u+1, which requires
// every block to have consumed tag u). hbuf pre-zeroed per call (replay-safe).
__global__ __launch_bounds__(256, 1) void lstm_seq(
    const float* __restrict__ xg,            // [B*U][4096] input proj + biases
    const unsigned short* __restrict__ Whh,  // [4096][1024] bf16 (this layer)
    unsigned short* __restrict__ xout,       // [B*U][1024] bf16 layer output
    float* __restrict__ hbuf)                // [2][B][1024] f32, zeroed before launch
{
  __shared__ float hs[2][H_];        // staged h (both batches)
  __shared__ float xgs[128][64];     // xg slice: [b*64+u][l]
  __shared__ float part[4][64][2];   // k-segment partials
  __shared__ float gv[2][64];        // gate pre-activations

  const int tid = threadIdx.x, bid = blockIdx.x;
  const int w = tid >> 6, l = tid & 63;
  const int g = l >> 4, q = l & 15;
  const int row = g * 1024 + bid * 16 + q;
  const int kb = w * 256;

  // ---- load this thread's Whh segment into VGPRs (once) ----
  bf16x8 wreg[32];
#pragma unroll
  for (int it = 0; it < 32; ++it)
    wreg[it] = *(const bf16x8*)&Whh[(long)row * H_ + kb + it * 8];

  // ---- stage this block's xg slice into LDS (once) ----
#pragma unroll
  for (int rep = 0; rep < 8; ++rep) {
    int c = rep * 256 + tid;                 // 2048 float4 chunks
    int r2 = c >> 4, sub = c & 15;           // r2 = b*64+u
    int gg = sub >> 2, f4 = sub & 3;
    const float4 v = *(const float4*)&xg[(long)r2 * 4096 + gg * 1024 + bid * 16 + f4 * 4];
    *(float4*)&xgs[r2][gg * 16 + f4 * 4] = v;
  }
  __syncthreads();

  float creg = 0.f;                          // c-state for threads tid<32: (b=tid>>4, q=tid&15)

  for (int u = 0; u < U_; ++u) {
    float a00 = 0.f, a01 = 0.f, a02 = 0.f, a03 = 0.f;
    float a10 = 0.f, a11 = 0.f, a12 = 0.f, a13 = 0.f;
    if (u > 0) {
      // ---- consume tag u: poll the 8 values this thread stages ----
      const float thr = 4.0f * u - 2.0f;
      const float* base = hbuf + (u & 1) * 2 * H_;
      const float* pa = base + tid * 4;          // batch 0, j = tid*4..+3
      const float* pb = base + H_ + tid * 4;     // batch 1
      float4 va, vb;
      for (;;) {
        asm volatile("global_load_dwordx4 %0, %2, off sc1\n\t"
                     "global_load_dwordx4 %1, %3, off sc1\n\t"
                     "s_waitcnt vmcnt(0)"
                     : "=v"(va), "=v"(vb) : "v"(pa), "v"(pb) : "memory");
        if (va.x > thr && va.y > thr && va.z > thr && va.w > thr &&
            vb.x > thr && vb.y > thr && vb.z > thr && vb.w > thr) break;
      }
      const float off = 4.0f * u;
      va.x -= off; va.y -= off; va.z -= off; va.w -= off;
      vb.x -= off; vb.y -= off; vb.z -= off; vb.w -= off;
      *(float4*)&hs[0][tid * 4] = va;
      *(float4*)&hs[1][tid * 4] = vb;
      __syncthreads();                        // SYNC-A: hs fully staged
      // ---- dot: float4 LDS reads (ds_read_b128) ----
#pragma unroll
      for (int it = 0; it < 32; ++it) {
        bf16x8 wv = wreg[it];
        float4 h0a = *(const float4*)&hs[0][kb + it * 8];
        float4 h0b = *(const float4*)&hs[0][kb + it * 8 + 4];
        float4 h1a = *(const float4*)&hs[1][kb + it * 8];
        float4 h1b = *(const float4*)&hs[1][kb + it * 8 + 4];
        a00 += bf2f((unsigned short)wv[0]) * h0a.x + bf2f((unsigned short)wv[4]) * h0b.x;
        a01 += bf2f((unsigned short)wv[1]) * h0a.y + bf2f((unsigned short)wv[5]) * h0b.y;
        a02 += bf2f((unsigned short)wv[2]) * h0a.z + bf2f((unsigned short)wv[6]) * h0b.z;
        a03 += bf2f((unsigned short)wv[3]) * h0a.w + bf2f((unsigned short)wv[7]) * h0b.w;
        a10 += bf2f((unsigned short)wv[0]) * h1a.x + bf2f((unsigned short)wv[4]) * h1b.x;
        a11 += bf2f((unsigned short)wv[1]) * h1a.y + bf2f((unsigned short)wv[5]) * h1b.y;
        a12 += bf2f((unsigned short)wv[2]) * h1a.z + bf2f((unsigned short)wv[6]) * h1b.z;
        a13 += bf2f((unsigned short)wv[3]) * h1a.w + bf2f((unsigned short)wv[7]) * h1b.w;
      }
    }
    part[w][l][0] = (a00 + a01) + (a02 + a03);
    part[w][l][1] = (a10 + a11) + (a12 + a13);
    __syncthreads();                          // SYNC-B
    if (tid < 128) {
      int b = tid >> 6, ll = tid & 63;
      gv[b][ll] = part[0][ll][b] + part[1][ll][b] + part[2][ll][b] + part[3][ll][b]
                + xgs[b * 64 + u][ll];
    }
    __syncthreads();                          // SYNC-C
    if (tid < 32) {
      int b = tid >> 4, qq = tid & 15;
      float gi = gv[b][qq], gf = gv[b][16 + qq], gc = gv[b][32 + qq], go = gv[b][48 + qq];
      float i_ = 1.f / (1.f + expf(-gi));
      float f_ = 1.f / (1.f + expf(-gf));
      float g_ = tanhf(gc);
      float o_ = 1.f / (1.f + expf(-go));
      creg = f_ * creg + i_ * g_;
      float h = o_ * tanhf(creg);
      int j = bid * 16 + qq;
      xout[(b * U_ + u) * H_ + j] = f2bf(h);
      if (u < U_ - 1) {
        // produce tag u+1: the tagged value IS the arrival signal
        float tv = h + 4.0f * (u + 1);
        const float* p = &hbuf[((u + 1) & 1) * 2 * H_ + b * H_ + j];
        asm volatile("global_store_dword %0, %1, off sc1"
                     :: "v"(p), "v"(tv) : "memory");
      }
    }
    // no end-of-step barrier: next step's LDS writes are ordered by SYNC-A/B/C,
    // and cross-block ordering is carried by the tags themselves
  }
}

// ---------------- joint = bf16(relu(enc_p[b,t,:] + prd_p[b,u,:])) ----------------
__global__ void k_joint(const float* __restrict__ ep, const float* __restrict__ pp,
                        unsigned short* __restrict__ jt)
{
  int idx = blockIdx.x * 256 + threadIdx.x;  // per float4; total 16384*256
  int m = idx >> 8;
  int kc = (idx & 255) << 2;
  int erow = m >> 6;                          // b*T + t
  int prow = (m >> 13) * U_ + (m & 63);       // b*U + u
  const float4 e = *(const float4*)&ep[erow * H_ + kc];
  const float4 p = *(const float4*)&pp[prow * H_ + kc];
  float4 s;
  s.x = fmaxf(e.x + p.x, 0.f); s.y = fmaxf(e.y + p.y, 0.f);
  s.z = fmaxf(e.z + p.z, 0.f); s.w = fmaxf(e.w + p.w, 0.f);
  ushort4 o; o.x = f2bf(s.x); o.y = f2bf(s.y); o.z = f2bf(s.z); o.w = f2bf(s.w);
  *(ushort4*)&jt[m * H_ + kc] = o;
}

extern "C" void kernel_launch(void* const* d_in, const int* in_sizes, int n_in,
                              void* d_out, int out_size, void* d_ws, size_t ws_size,
                              hipStream_t stream)
{
  const float* enc   = (const float*)d_in[0];
  const int*   tg    = (const int*)d_in[1];
  const float* em    = (const float*)d_in[2];
  const float* Wih   = (const float*)d_in[3];
  const float* Whh   = (const float*)d_in[4];
  const float* bih   = (const float*)d_in[5];
  const float* bhh   = (const float*)d_in[6];
  const float* encW  = (const float*)d_in[7];
  const float* encB  = (const float*)d_in[8];
  const float* prdW  = (const float*)d_in[9];
  const float* prdB  = (const float*)d_in[10];
  const float* outW  = (const float*)d_in[11];
  const float* outB  = (const float*)d_in[12];
  float* out = (float*)d_out;
  char* ws = (char*)d_ws;

  // workspace layout (bytes); outW_bf padded to 5120 rows for unmasked staging
  unsigned short* outW_bf = (unsigned short*)(ws + 0);         // 5120*1024*2 = 10,485,760
  unsigned short* Wih_bf  = (unsigned short*)(ws + 10485760);  // 2*4096*1024*2
  unsigned short* Whh_bf  = (unsigned short*)(ws + 27262976);  // 2*4096*1024*2
  unsigned short* encW_bf = (unsigned short*)(ws + 44040192);  // 1024*1024*2
  unsigned short* prdW_bf = (unsigned short*)(ws + 46137344);  // 1024*1024*2
  unsigned short* enc_bf  = (unsigned short*)(ws + 48234496);  // 256*1024*2
  unsigned short* x0_bf   = (unsigned short*)(ws + 48758784);  // 128*1024*2
  unsigned short* x1_bf   = (unsigned short*)(ws + 49020928);  // 128*1024*2
  unsigned short* x2_bf   = (unsigned short*)(ws + 49283072);  // 128*1024*2
  float* xg  = (float*)(ws + 49545216);                        // 128*4096*4 = 2,097,152
  float* hbufL0 = (float*)(ws + 51642368);                     // [2][2][1024] f32 = 16,384
  unsigned short* jt = (unsigned short*)(ws + 51659008);       // 16384*1024*2 -> ends 85,213,440
  float* hbufL1 = (float*)(ws + 85213440);                     // 16,384 (ws proven >= 86.5 MB)
  // ep/pp overlap xg (xg is dead once both lstm_seq are done)
  float* ep = xg;                                              // 256*1024*4 = 1,048,576
  float* pp = (float*)(ws + 49545216 + 1048576);               // 128*1024*4

  // zero both layers' h ping-pong buffers (tag baseline; replay-safe)
  hipMemsetAsync(hbufL0, 0, 16384, stream);
  hipMemsetAsync(hbufL1, 0, 16384, stream);

  // weight / activation conversions to bf16
  {
    int n4;
    n4 = (NO_ * H_) >> 2;        k_cvt<<<(n4 + 255) / 256, 256, 0, stream>>>(outW, outW_bf, n4);
    n4 = (2 * 4096 * H_) >> 2;   k_cvt<<<(n4 + 255) / 256, 256, 0, stream>>>(Wih, Wih_bf, n4);
    n4 = (2 * 4096 * H_) >> 2;   k_cvt<<<(n4 + 255) / 256, 256, 0, stream>>>(Whh, Whh_bf, n4);
    n4 = (H_ * H_) >> 2;         k_cvt<<<(n4 + 255) / 256, 256, 0, stream>>>(encW, encW_bf, n4);
    n4 = (H_ * H_) >> 2;         k_cvt<<<(n4 + 255) / 256, 256, 0, stream>>>(prdW, prdW_bf, n4);
    n4 = (B_ * T_ * H_) >> 2;    k_cvt<<<(n4 + 255) / 256, 256, 0, stream>>>(enc, enc_bf, n4);
  }
  k_embed<<<(B_ * U_ * H_ / 4) / 256, 256, 0, stream>>>(tg, em, x0_bf);

  // ---- LSTM layer 0 ----
  gemm_bt<<<dim3(32, 1), 256, 0, stream>>>(x0_bf, Wih_bf, bih, bhh, xg, B_ * U_, 4096, H_);
  lstm_seq<<<64, 256, 0, stream>>>(xg, Whh_bf, x1_bf, hbufL0);
  // ---- LSTM layer 1 ----
  gemm_bt<<<dim3(32, 1), 256, 0, stream>>>(x1_bf, Wih_bf + 4096 * H_, bih + 4096, bhh + 4096,
                                           xg, B_ * U_, 4096, H_);
  lstm_seq<<<64, 256, 0, stream>>>(xg, Whh_bf + 4096 * H_, x2_bf, hbufL1);

  // ---- projections ----
  gemm_bt<<<dim3(8, 2), 256, 0, stream>>>(enc_bf, encW_bf, encB, nullptr, ep, B_ * T_, H_, H_);
  gemm_bt<<<dim3(8, 1), 256, 0, stream>>>(x2_bf, prdW_bf, prdB, nullptr, pp, B_ * U_, H_, H_);

  // ---- joint + logits ----
  k_joint<<<16384, 256, 0, stream>>>(ep, pp, jt);
  gemm_bt<<<dim3((NO_ + 127) / 128, B_ * T_ * U_ / 128), 256, 0, stream>>>(
      jt, outW_bf, outB, nullptr, out, B_ * T_ * U_, NO_, H_);
}